// Round 14
// baseline (158.162 us; speedup 1.0000x reference)
//
#include <hip/hip_runtime.h>
#include <hip/hip_bf16.h>

// Problem constants
#define M_DIM 256     // B*T
#define K_DIM 8192
#define N_DIM 8192
#define NGRP  64      // N/128 groups

// Tile config (R10 structure: 8 waves = 4m x 2n, 2 blocks/CU)
#define BN 128        // W rows per block
#define BK 32         // n per step
#define THREADS 512
#define SPLITN 8
#define CHUNK  (N_DIM / SPLITN)   // 1024
#define NSTEPS (CHUNK / BK)       // 32
#define NPAIRS (NSTEPS / 2)       // 16
#define NG     (CHUNK >> 7)       // 8 groups per chunk

// LDS: A triple-buffered (global_load_lds) + B double-buffered bf16 + scales
#define ASIZE 16384               // bf16 [256][32]
#define BSIZE 8192                // bf16 [128][32]
#define B_OFF  (3 * ASIZE)        // 49152
#define SL_OFF (B_OFF + 2 * BSIZE)            // 65536
#define LDS_TOTAL (SL_OFF + NG * 128 * 8)     // 73728 (72KB) -> 2 blocks/CU

typedef __bf16 bf16x8 __attribute__((ext_vector_type(8)));
typedef __bf16 bf16x4 __attribute__((ext_vector_type(4)));
typedef float  f32x4  __attribute__((ext_vector_type(4)));

// XOR swizzle (involution): slot bits [6:4] ^= row bits [9:7]. Used for A and B.
#define SW(a) ((a) ^ ((((a) >> 7) & 7) << 4))

#define GLOAD_LDS16(g, l) __builtin_amdgcn_global_load_lds( \
    (const __attribute__((address_space(1))) void*)(g),     \
    (__attribute__((address_space(3))) void*)(l), 16, 0, 0)

// pair-granular n-rotation: both steps of a pair map to adjacent actual steps
#define SMAP(t) ((((((t) >> 1) + startp) & (NPAIRS - 1)) << 1) | ((t) & 1))

// ---------------- Kernel 0: xs[m,n] = bf16(x[m,n] * mu1[n]) ----------------
__global__ __launch_bounds__(256) void prep_xs(const float* __restrict__ x,
                                               const float* __restrict__ mu1,
                                               __bf16* __restrict__ xs) {
    int t  = blockIdx.x * 256 + threadIdx.x;
    int n4 = t & 2047;
    int m  = t >> 11;
    int n  = n4 << 2;
    float4 xv = *(const float4*)(x + (size_t)m * N_DIM + n);
    float4 mv = *(const float4*)(mu1 + n);
    bf16x4 o;
    o[0] = (__bf16)(xv.x * mv.x);
    o[1] = (__bf16)(xv.y * mv.y);
    o[2] = (__bf16)(xv.z * mv.z);
    o[3] = (__bf16)(xv.w * mv.w);
    *(bf16x4*)(xs + (size_t)m * N_DIM + n) = o;
}

// ---------------- Kernel 1: R10 + plain-load B pair-fetch (256B/row-visit) ----------------
__global__ __launch_bounds__(THREADS, 4)
void gemm_q(const __bf16* __restrict__ xs, const int* __restrict__ Wq,
            const float* __restrict__ scales, const float* __restrict__ zeros,
            __bf16* __restrict__ partial) {
    extern __shared__ __align__(1024) char lds[];

    const int b     = blockIdx.x;      // 512 blocks
    const int split = b & 7;           // XCD-affine split
    const int kidx  = b >> 3;          // 0..63
    const int k0    = kidx * BN;
    const int nbase = split * CHUNK;
    const int gbase = split * NG;

    const int tid  = threadIdx.x;
    const int lane = tid & 63;
    const int w    = tid >> 6;   // 0..7
    const int wmq  = w >> 1;     // m quarter (64 rows)
    const int wnh  = w & 1;      // k half (64 cols)
    const int startp = kidx & (NPAIRS - 1);  // pair-granular n-rotation

    float* SL = (float*)(lds + SL_OFF);      // [NG][128] x {s, -z*s}

    // ---- stage scales/zeros (once) ----
    {
        int r = tid >> 2, gq = tid & 3;
#pragma unroll
        for (int gg = 0; gg < (NG >> 2); ++gg) {
            int g = (gg << 2) | gq;
            size_t si = (size_t)(k0 + r) * NGRP + gbase + g;
            float s = scales[si];
            float z = zeros[si];
            float2 v; v.x = s; v.y = -z * s;
            *(float2*)&SL[(size_t)((g << 7) + r) * 2] = v;
        }
    }
    // full drain so the vmcnt ledger starts at 0
    asm volatile("s_waitcnt vmcnt(0) lgkmcnt(0)" ::: "memory");
    __builtin_amdgcn_s_barrier();

    // ---- A staging via global_load_lds: 2x 1KB chunks per wave ----
    const char* asrc[2];
    int aoff[2];
#pragma unroll
    for (int cc = 0; cc < 2; ++cc) {
        int c   = w * 2 + cc;            // 0..15
        int off = c * 1024 + lane * 16;  // linear LDS dest
        int L   = SW(off);               // inverse-swizzled source element
        aoff[cc] = off;
        asrc[cc] = (const char*)xs + ((size_t)(L >> 6) * N_DIM) * 2 + (L & 63);
    }

    // ---- B staging: lane owns row 16w+(l>>2), 8 codes at col (l&3)*8 ----
    const int brow = w * 16 + (lane >> 2);        // 0..127
    const int bq   = lane & 3;
    const int* bptr0 = Wq + (size_t)(k0 + brow) * N_DIM + bq * 8;
    char* bdst0 = lds + B_OFF + SW(brow * 64 + bq * 16);  // swizzled B write

    // B frag read offsets (4 ci tiles), A frag read offsets (4 mi tiles)
    int rb[4], ra[4];
#pragma unroll
    for (int i = 0; i < 4; ++i) {
        rb[i] = SW((wnh * 64 + i * 16 + (lane & 15)) * 64 + (lane >> 4) * 16);
        ra[i] = SW((wmq * 64 + i * 16 + (lane & 15)) * 64 + (lane >> 4) * 16);
    }

    // rotating A buffers: pA0 = read(s), pA1 = s+1, pA2 = issue target (s+2)
    char* pA0 = lds;
    char* pA1 = lds + ASIZE;
    char* pA2 = lds + 2 * ASIZE;

#define ISSUE_A(t, pbuf)                                                  \
    {                                                                     \
        int s_ = SMAP(t);                                                 \
        size_t so_ = (size_t)(nbase + s_ * BK) * 2;                       \
        GLOAD_LDS16(asrc[0] + so_, (pbuf) + aoff[0]);                     \
        GLOAD_LDS16(asrc[1] + so_, (pbuf) + aoff[1]);                     \
    }
// load BOTH steps of the pair at even step t: 256B contiguous per W row
#define LOAD_BPAIR(t, a0, a1, a2, a3)                                     \
    {                                                                     \
        int s_ = SMAP(t);                                                 \
        const int* p_ = bptr0 + (nbase + s_ * BK);                        \
        a0 = *(const int4*)p_;                                            \
        a1 = *(const int4*)(p_ + 4);                                      \
        a2 = *(const int4*)(p_ + 32);                                     \
        a3 = *(const int4*)(p_ + 36);                                     \
    }

    f32x4 acc[4][4];
#pragma unroll
    for (int i = 0; i < 4; ++i)
#pragma unroll
        for (int j = 0; j < 4; ++j)
            acc[i][j] = (f32x4){0.f, 0.f, 0.f, 0.f};

    int4 pq0, pq1, pq2, pq3, rq0, rq1, rq2, rq3;

    // prologue FIFO: [Bp0(4) | A0(2) | A1(2) | Bp2(4)] = 12 outstanding
    LOAD_BPAIR(0, pq0, pq1, pq2, pq3);
    asm volatile("" ::: "memory");
    ISSUE_A(0, pA0);
    asm volatile("" ::: "memory");
    ISSUE_A(1, pA1);
    asm volatile("" ::: "memory");
    LOAD_BPAIR(2, rq0, rq1, rq2, rq3);

    // STEP: vmcnt(W) [B regs + A(it) landed] | dequant B(it)->LDS[it&1] |
    // BLOAD (odd steps: pair it+3/it+4 window into just-consumed regs) |
    // lgkm+barrier | B frags | issue A(it+2) | MFMA on pA0 | rotate.
    // Ledger: steady entry even=[Bp(it)4,A(it)2,A(it+1)2,Bp(it+2)4]=12 -> vmcnt(6)
    //         odd =[A(it)2,Bp(it+1)4,A(it+1)2]=8 -> drain A(it) -> vmcnt(6)
    //         tail: 6 / 6 / 2 / 0 (derived stepwise).
#define STEP(it, q0c, q1c, WSTR, BLOAD, DO_A)                             \
    {                                                                     \
        asm volatile("s_waitcnt vmcnt(" WSTR ")" ::: "memory");           \
        int scur_ = SMAP(it);                                             \
        float2 sz_ = *(float2*)&SL[(size_t)(((scur_ >> 2) << 7) + brow) * 2]; \
        bf16x8 wv_;                                                       \
        wv_[0] = (__bf16)((float)q0c.x * sz_.x + sz_.y);                  \
        wv_[1] = (__bf16)((float)q0c.y * sz_.x + sz_.y);                  \
        wv_[2] = (__bf16)((float)q0c.z * sz_.x + sz_.y);                  \
        wv_[3] = (__bf16)((float)q0c.w * sz_.x + sz_.y);                  \
        wv_[4] = (__bf16)((float)q1c.x * sz_.x + sz_.y);                  \
        wv_[5] = (__bf16)((float)q1c.y * sz_.x + sz_.y);                  \
        wv_[6] = (__bf16)((float)q1c.z * sz_.x + sz_.y);                  \
        wv_[7] = (__bf16)((float)q1c.w * sz_.x + sz_.y);                  \
        *(bf16x8*)(bdst0 + ((it) & 1) * BSIZE) = wv_;                     \
        BLOAD;                                                            \
        asm volatile("s_waitcnt lgkmcnt(0)" ::: "memory");                \
        __builtin_amdgcn_s_barrier();                                     \
        const char* bufB_ = lds + B_OFF + ((it) & 1) * BSIZE;             \
        bf16x8 bv0_ = *(const bf16x8*)(bufB_ + rb[0]);                    \
        bf16x8 bv1_ = *(const bf16x8*)(bufB_ + rb[1]);                    \
        bf16x8 bv2_ = *(const bf16x8*)(bufB_ + rb[2]);                    \
        bf16x8 bv3_ = *(const bf16x8*)(bufB_ + rb[3]);                    \
        if (DO_A) { ISSUE_A((it) + 2, pA2); }                             \
        __builtin_amdgcn_s_setprio(1);                                    \
        _Pragma("unroll")                                                 \
        for (int mi = 0; mi < 4; ++mi) {                                  \
            bf16x8 av_ = *(const bf16x8*)(pA0 + ra[mi]);                  \
            acc[mi][0] = __builtin_amdgcn_mfma_f32_16x16x32_bf16(av_, bv0_, acc[mi][0], 0, 0, 0); \
            acc[mi][1] = __builtin_amdgcn_mfma_f32_16x16x32_bf16(av_, bv1_, acc[mi][1], 0, 0, 0); \
            acc[mi][2] = __builtin_amdgcn_mfma_f32_16x16x32_bf16(av_, bv2_, acc[mi][2], 0, 0, 0); \
            acc[mi][3] = __builtin_amdgcn_mfma_f32_16x16x32_bf16(av_, bv3_, acc[mi][3], 0, 0, 0); \
        }                                                                 \
        __builtin_amdgcn_s_setprio(0);                                    \
        { char* t_ = pA0; pA0 = pA1; pA1 = pA2; pA2 = t_; }               \
    }

#define NOB {}
    for (int it = 0; it < NSTEPS - 4; it += 4) {
        STEP(it,     pq0, pq1, "6", NOB, true);
        STEP(it + 1, pq2, pq3, "6", LOAD_BPAIR((it) + 4, pq0, pq1, pq2, pq3), true);
        STEP(it + 2, rq0, rq1, "6", NOB, true);
        STEP(it + 3, rq2, rq3, "6", LOAD_BPAIR((it) + 6, rq0, rq1, rq2, rq3), true);
    }
    STEP(NSTEPS - 4, pq0, pq1, "6", NOB, true);    // step 28: issues A(30)
    STEP(NSTEPS - 3, pq2, pq3, "6", NOB, true);    // step 29: issues A(31)
    STEP(NSTEPS - 2, rq0, rq1, "2", NOB, false);
    STEP(NSTEPS - 1, rq2, rq3, "0", NOB, false);
#undef NOB
#undef STEP
#undef ISSUE_A
#undef LOAD_BPAIR

    // ---- epilogue: bf16 partials (C/D: col=lane&15, row=(lane>>4)*4+reg) ----
    __bf16* outp = partial + (size_t)split * ((size_t)M_DIM * K_DIM);
#pragma unroll
    for (int mi = 0; mi < 4; ++mi) {
#pragma unroll
        for (int ci = 0; ci < 4; ++ci) {
            int gk = k0 + wnh * 64 + ci * 16 + (lane & 15);
            int gm = wmq * 64 + mi * 16 + (lane >> 4) * 4;
#pragma unroll
            for (int rix = 0; rix < 4; ++rix)
                outp[(size_t)(gm + rix) * K_DIM + gk] = (__bf16)acc[mi][ci][rix];
        }
    }
}

// ---------------- Kernel 2: out = mu2[k] * sum_splits + bias[k] ----------------
__global__ __launch_bounds__(256) void reduce_out(const __bf16* __restrict__ partial,
                                                  const float* __restrict__ mu2,
                                                  const float* __restrict__ bias,
                                                  float* __restrict__ out) {
    int t  = blockIdx.x * 256 + threadIdx.x;
    int k4 = t & 2047;
    int m  = t >> 11;
    size_t base = (size_t)m * K_DIM + (size_t)k4 * 4;
    float4 s; s.x = 0.f; s.y = 0.f; s.z = 0.f; s.w = 0.f;
#pragma unroll
    for (int sp = 0; sp < SPLITN; ++sp) {
        bf16x4 p = *(const bf16x4*)(partial + (size_t)sp * ((size_t)M_DIM * K_DIM) + base);
        s.x += (float)p[0]; s.y += (float)p[1]; s.z += (float)p[2]; s.w += (float)p[3];
    }
    float4 m2 = *(const float4*)(mu2 + (size_t)k4 * 4);
    float4 bi = *(const float4*)(bias + (size_t)k4 * 4);
    float4 o;
    o.x = s.x * m2.x + bi.x;
    o.y = s.y * m2.y + bi.y;
    o.z = s.z * m2.z + bi.z;
    o.w = s.w * m2.w + bi.w;
    *(float4*)(out + base) = o;
}

extern "C" void kernel_launch(void* const* d_in, const int* in_sizes, int n_in,
                              void* d_out, int out_size, void* d_ws, size_t ws_size,
                              hipStream_t stream) {
    const float* x      = (const float*)d_in[0];
    const int*   Wq     = (const int*)d_in[1];
    const float* scales = (const float*)d_in[2];
    const float* zeros  = (const float*)d_in[3];
    const float* mu1    = (const float*)d_in[4];
    const float* mu2    = (const float*)d_in[5];
    const float* bias   = (const float*)d_in[6];
    float* out = (float*)d_out;

    __bf16* xs = (__bf16*)d_ws;                                        // 4 MB
    const size_t xs_bytes = (size_t)M_DIM * N_DIM * sizeof(__bf16);
    __bf16* partial = (__bf16*)((char*)d_ws + xs_bytes);               // 8 x 4 MB

    (void)hipFuncSetAttribute((const void*)gemm_q,
                              hipFuncAttributeMaxDynamicSharedMemorySize,
                              LDS_TOTAL);

    prep_xs<<<2048, 256, 0, stream>>>(x, mu1, xs);
    gemm_q<<<64 * SPLITN, THREADS, LDS_TOTAL, stream>>>(xs, Wq, scales, zeros, partial);
    reduce_out<<<2048, 256, 0, stream>>>(partial, mu2, bias, out);
}

// Round 15
// 84.539 us; speedup vs baseline: 1.8709x; 1.8709x over previous
//
#include <hip/hip_runtime.h>
#include <hip/hip_bf16.h>

// Problem constants
#define M_DIM 256     // B*T
#define K_DIM 8192
#define N_DIM 8192
#define NGRP  64      // N/128 groups

// Tile config (R10 structure: 8 waves = 4m x 2n, 2 blocks/CU)
#define BN 128        // W rows per block
#define BK 32         // n per step
#define THREADS 512   // 8 waves: 4 (m) x 2 (k)
#define SPLITN 8
#define CHUNK  (N_DIM / SPLITN)   // 1024
#define NSTEPS (CHUNK / BK)       // 32
#define NG     (CHUNK >> 7)       // 8 groups per chunk

// LDS: A triple-buffered (global_load_lds) + B double-buffered bf16 + scales
#define ASIZE 16384               // bf16 [256][32]
#define BSIZE 8192                // bf16 [128][32]
#define B_OFF  (3 * ASIZE)        // 49152
#define SL_OFF (B_OFF + 2 * BSIZE)            // 65536
#define LDS_TOTAL (SL_OFF + NG * 128 * 8)     // 73728 (72KB) -> 2 blocks/CU

typedef __bf16 bf16x8 __attribute__((ext_vector_type(8)));
typedef __bf16 bf16x4 __attribute__((ext_vector_type(4)));
typedef float  f32x4  __attribute__((ext_vector_type(4)));

// XOR swizzle (involution): slot bits [6:4] ^= row bits [9:7]. Used for A and B.
#define SW(a) ((a) ^ ((((a) >> 7) & 7) << 4))

#define GLOAD_LDS16(g, l) __builtin_amdgcn_global_load_lds( \
    (const __attribute__((address_space(1))) void*)(g),     \
    (__attribute__((address_space(3))) void*)(l), 16, 0, 0)

// ---------------- Kernel 0: xs[m,n] = bf16(x[m,n] * mu1[n]) ----------------
__global__ __launch_bounds__(256) void prep_xs(const float* __restrict__ x,
                                               const float* __restrict__ mu1,
                                               __bf16* __restrict__ xs) {
    int t  = blockIdx.x * 256 + threadIdx.x;
    int n4 = t & 2047;
    int m  = t >> 11;
    int n  = n4 << 2;
    float4 xv = *(const float4*)(x + (size_t)m * N_DIM + n);
    float4 mv = *(const float4*)(mu1 + n);
    bf16x4 o;
    o[0] = (__bf16)(xv.x * mv.x);
    o[1] = (__bf16)(xv.y * mv.y);
    o[2] = (__bf16)(xv.z * mv.z);
    o[3] = (__bf16)(xv.w * mv.w);
    *(bf16x4*)(xs + (size_t)m * N_DIM + n) = o;
}

// ---------------- Kernel 1: 4m x 2n waves, single-wait pipelined GEMM ----------------
__global__ __launch_bounds__(THREADS, 4)
void gemm_q(const __bf16* __restrict__ xs, const int* __restrict__ Wq,
            const float* __restrict__ scales, const float* __restrict__ zeros,
            __bf16* __restrict__ partial) {
    extern __shared__ __align__(1024) char lds[];

    const int b     = blockIdx.x;      // 512 blocks
    const int split = b & 7;           // XCD-affine split
    const int kidx  = b >> 3;          // 0..63
    const int k0    = kidx * BN;
    const int nbase = split * CHUNK;
    const int gbase = split * NG;

    const int tid  = threadIdx.x;
    const int lane = tid & 63;
    const int w    = tid >> 6;   // 0..7
    const int wmq  = w >> 1;     // m quarter (64 rows)
    const int wnh  = w & 1;      // k half (64 cols)
    const int start = kidx & (NSTEPS - 1);   // n-rotation

    float* SL = (float*)(lds + SL_OFF);      // [NG][128] x {s, -z*s}

    // ---- stage scales/zeros (once) ----
    {
        int r = tid >> 2, gq = tid & 3;
#pragma unroll
        for (int gg = 0; gg < (NG >> 2); ++gg) {
            int g = (gg << 2) | gq;
            size_t si = (size_t)(k0 + r) * NGRP + gbase + g;
            float s = scales[si];
            float z = zeros[si];
            float2 v; v.x = s; v.y = -z * s;
            *(float2*)&SL[(size_t)((g << 7) + r) * 2] = v;
        }
    }
    // full drain so the vmcnt ledger starts at 0
    asm volatile("s_waitcnt vmcnt(0) lgkmcnt(0)" ::: "memory");
    __builtin_amdgcn_s_barrier();

    // ---- A staging via global_load_lds: 2x 1KB chunks per wave ----
    const char* asrc[2];
    int aoff[2];
#pragma unroll
    for (int cc = 0; cc < 2; ++cc) {
        int c   = w * 2 + cc;            // 0..15
        int off = c * 1024 + lane * 16;  // linear LDS dest
        int L   = SW(off);               // inverse-swizzled source element
        aoff[cc] = off;
        asrc[cc] = (const char*)xs + ((size_t)(L >> 6) * N_DIM) * 2 + (L & 63);
    }

    // ---- B staging: lane owns row 16w+(l>>2), 8 codes at col (l&3)*8 ----
    const int brow = w * 16 + (lane >> 2);        // 0..127
    const int bq   = lane & 3;
    const int* bptr0 = Wq + (size_t)(k0 + brow) * N_DIM + bq * 8;
    char* bdst0 = lds + B_OFF + SW(brow * 64 + bq * 16);  // swizzled B write

    // B frag read offsets (4 ci tiles), A frag read offsets (4 mi tiles)
    int rb[4], ra[4];
#pragma unroll
    for (int i = 0; i < 4; ++i) {
        rb[i] = SW((wnh * 64 + i * 16 + (lane & 15)) * 64 + (lane >> 4) * 16);
        ra[i] = SW((wmq * 64 + i * 16 + (lane & 15)) * 64 + (lane >> 4) * 16);
    }

    // rotating A buffers: pA0 = read(s), pA1 = s+1, pA2 = issue target (s+2)
    char* pA0 = lds;
    char* pA1 = lds + ASIZE;
    char* pA2 = lds + 2 * ASIZE;

#define ISSUE_A(t, pbuf)                                                  \
    {                                                                     \
        int s_ = ((t) + start) & (NSTEPS - 1);                            \
        size_t so_ = (size_t)(nbase + s_ * BK) * 2;                       \
        GLOAD_LDS16(asrc[0] + so_, (pbuf) + aoff[0]);                     \
        GLOAD_LDS16(asrc[1] + so_, (pbuf) + aoff[1]);                     \
    }
#define LOAD_B(t, q0, q1)                                                 \
    {                                                                     \
        int s_ = ((t) + start) & (NSTEPS - 1);                            \
        const int* p_ = bptr0 + (nbase + s_ * BK);                        \
        q0 = *(const int4*)p_;                                            \
        q1 = *(const int4*)(p_ + 4);                                      \
    }

    f32x4 acc[4][4];
#pragma unroll
    for (int i = 0; i < 4; ++i)
#pragma unroll
        for (int j = 0; j < 4; ++j)
            acc[i][j] = (f32x4){0.f, 0.f, 0.f, 0.f};

    int4 qa0, qa1, qb0, qb1;

    // prologue (alternating so steady vmcnt(4) drains exactly {B(s),A(s)}):
    // FIFO: B0, A0, B1, A1
    LOAD_B(0, qa0, qa1);
    asm volatile("" ::: "memory");
    ISSUE_A(0, pA0);
    asm volatile("" ::: "memory");
    LOAD_B(1, qb0, qb1);
    asm volatile("" ::: "memory");
    ISSUE_A(1, pA1);

    // STEP: vmcnt(W1) [B(s),A(s) landed] | dequant B(s)->bf16[s&1] |
    //       issue B(s+2) | lgkm+barrier | frags | issue A(s+2) | MFMA | rotate
#define STEP(it, q0c, q1c, W1N, DO_ISS)                                   \
    {                                                                     \
        asm volatile("s_waitcnt vmcnt(" #W1N ")" ::: "memory");           \
        int scur_ = ((it) + start) & (NSTEPS - 1);                        \
        float2 sz_ = *(float2*)&SL[(size_t)(((scur_ >> 2) << 7) + brow) * 2]; \
        bf16x8 wv_;                                                       \
        wv_[0] = (__bf16)((float)q0c.x * sz_.x + sz_.y);                  \
        wv_[1] = (__bf16)((float)q0c.y * sz_.x + sz_.y);                  \
        wv_[2] = (__bf16)((float)q0c.z * sz_.x + sz_.y);                  \
        wv_[3] = (__bf16)((float)q0c.w * sz_.x + sz_.y);                  \
        wv_[4] = (__bf16)((float)q1c.x * sz_.x + sz_.y);                  \
        wv_[5] = (__bf16)((float)q1c.y * sz_.x + sz_.y);                  \
        wv_[6] = (__bf16)((float)q1c.z * sz_.x + sz_.y);                  \
        wv_[7] = (__bf16)((float)q1c.w * sz_.x + sz_.y);                  \
        *(bf16x8*)(bdst0 + ((it) & 1) * BSIZE) = wv_;                     \
        if (DO_ISS) { LOAD_B((it) + 2, q0c, q1c); }                       \
        asm volatile("s_waitcnt lgkmcnt(0)" ::: "memory");                \
        __builtin_amdgcn_s_barrier();                                     \
        const char* bufB_ = lds + B_OFF + ((it) & 1) * BSIZE;             \
        bf16x8 bv0_ = *(const bf16x8*)(bufB_ + rb[0]);                    \
        bf16x8 bv1_ = *(const bf16x8*)(bufB_ + rb[1]);                    \
        bf16x8 bv2_ = *(const bf16x8*)(bufB_ + rb[2]);                    \
        bf16x8 bv3_ = *(const bf16x8*)(bufB_ + rb[3]);                    \
        if (DO_ISS) { ISSUE_A((it) + 2, pA2); }                           \
        __builtin_amdgcn_s_setprio(1);                                    \
        _Pragma("unroll")                                                 \
        for (int mi = 0; mi < 4; ++mi) {                                  \
            bf16x8 av_ = *(const bf16x8*)(pA0 + ra[mi]);                  \
            acc[mi][0] = __builtin_amdgcn_mfma_f32_16x16x32_bf16(av_, bv0_, acc[mi][0], 0, 0, 0); \
            acc[mi][1] = __builtin_amdgcn_mfma_f32_16x16x32_bf16(av_, bv1_, acc[mi][1], 0, 0, 0); \
            acc[mi][2] = __builtin_amdgcn_mfma_f32_16x16x32_bf16(av_, bv2_, acc[mi][2], 0, 0, 0); \
            acc[mi][3] = __builtin_amdgcn_mfma_f32_16x16x32_bf16(av_, bv3_, acc[mi][3], 0, 0, 0); \
        }                                                                 \
        __builtin_amdgcn_s_setprio(0);                                    \
        { char* t_ = pA0; pA0 = pA1; pA1 = pA2; pA2 = t_; }               \
    }

    // steady: s = 0..29 (issues on); peel 30 (no issues), 31 (drain)
    for (int it = 0; it < NSTEPS - 2; it += 2) {
        STEP(it,     qa0, qa1, 4, true);
        STEP(it + 1, qb0, qb1, 4, true);
    }
    STEP(NSTEPS - 2, qa0, qa1, 4, false);
    STEP(NSTEPS - 1, qb0, qb1, 0, false);
#undef STEP
#undef ISSUE_A
#undef LOAD_B

    // ---- epilogue: bf16 partials (C/D: col=lane&15, row=(lane>>4)*4+reg) ----
    __bf16* outp = partial + (size_t)split * ((size_t)M_DIM * K_DIM);
#pragma unroll
    for (int mi = 0; mi < 4; ++mi) {
#pragma unroll
        for (int ci = 0; ci < 4; ++ci) {
            int gk = k0 + wnh * 64 + ci * 16 + (lane & 15);
            int gm = wmq * 64 + mi * 16 + (lane >> 4) * 4;
#pragma unroll
            for (int rix = 0; rix < 4; ++rix)
                outp[(size_t)(gm + rix) * K_DIM + gk] = (__bf16)acc[mi][ci][rix];
        }
    }
}

// ---------------- Kernel 2: out = mu2[k] * sum_splits + bias[k] ----------------
__global__ __launch_bounds__(256) void reduce_out(const __bf16* __restrict__ partial,
                                                  const float* __restrict__ mu2,
                                                  const float* __restrict__ bias,
                                                  float* __restrict__ out) {
    int t  = blockIdx.x * 256 + threadIdx.x;
    int k4 = t & 2047;
    int m  = t >> 11;
    size_t base = (size_t)m * K_DIM + (size_t)k4 * 4;
    float4 s; s.x = 0.f; s.y = 0.f; s.z = 0.f; s.w = 0.f;
#pragma unroll
    for (int sp = 0; sp < SPLITN; ++sp) {
        bf16x4 p = *(const bf16x4*)(partial + (size_t)sp * ((size_t)M_DIM * K_DIM) + base);
        s.x += (float)p[0]; s.y += (float)p[1]; s.z += (float)p[2]; s.w += (float)p[3];
    }
    float4 m2 = *(const float4*)(mu2 + (size_t)k4 * 4);
    float4 bi = *(const float4*)(bias + (size_t)k4 * 4);
    float4 o;
    o.x = s.x * m2.x + bi.x;
    o.y = s.y * m2.y + bi.y;
    o.z = s.z * m2.z + bi.z;
    o.w = s.w * m2.w + bi.w;
    *(float4*)(out + base) = o;
}

extern "C" void kernel_launch(void* const* d_in, const int* in_sizes, int n_in,
                              void* d_out, int out_size, void* d_ws, size_t ws_size,
                              hipStream_t stream) {
    const float* x      = (const float*)d_in[0];
    const int*   Wq     = (const int*)d_in[1];
    const float* scales = (const float*)d_in[2];
    const float* zeros  = (const float*)d_in[3];
    const float* mu1    = (const float*)d_in[4];
    const float* mu2    = (const float*)d_in[5];
    const float* bias   = (const float*)d_in[6];
    float* out = (float*)d_out;

    __bf16* xs = (__bf16*)d_ws;                                        // 4 MB
    const size_t xs_bytes = (size_t)M_DIM * N_DIM * sizeof(__bf16);
    __bf16* partial = (__bf16*)((char*)d_ws + xs_bytes);               // 8 x 4 MB

    (void)hipFuncSetAttribute((const void*)gemm_q,
                              hipFuncAttributeMaxDynamicSharedMemorySize,
                              LDS_TOTAL);

    prep_xs<<<2048, 256, 0, stream>>>(x, mu1, xs);
    gemm_q<<<64 * SPLITN, THREADS, LDS_TOTAL, stream>>>(xs, Wq, scales, zeros, partial);
    reduce_out<<<2048, 256, 0, stream>>>(partial, mu2, bias, out);
}